// Round 15
// baseline (128.799 us; speedup 1.0000x reference)
//
#include <hip/hip_runtime.h>
#include <math.h>

#define B_ 4
#define H_ 8
#define L_ 1024
#define E_ 64
#define NTOP 35
#define SCALE_ 0.04419417382415922f  /* 1/sqrt(512) */

// ============================ device roles =================================

// ---- transpose staging x[b][t][h][e] -> xt[bh][e][t] (q and k) -------------
__device__ __forceinline__ void dev_stage(char* smem, int vbid,
                                          const float* __restrict__ q_g,
                                          const float* __restrict__ k_g,
                                          float* __restrict__ xtq,
                                          float* __restrict__ xtk) {
  float* tile = reinterpret_cast<float*>(smem);   // [64][65]
  const int tc = vbid & 15;
  const int src = (vbid >> 4) & 1;
  const int bh = vbid >> 5;
  const int b = bh >> 3, h = bh & 7;
  const int t0 = tc * 64;
  const int tid = threadIdx.x;
  const float* in = src ? k_g : q_g;
  float* out = src ? xtk : xtq;

  for (int idx = tid; idx < 1024; idx += 256) {
    int t = idx >> 4, e4 = idx & 15;
    float4 v = reinterpret_cast<const float4*>(
        in + ((size_t)(b * L_ + t0 + t) * H_ + h) * E_)[e4];
    tile[t * 65 + e4 * 4 + 0] = v.x; tile[t * 65 + e4 * 4 + 1] = v.y;
    tile[t * 65 + e4 * 4 + 2] = v.z; tile[t * 65 + e4 * 4 + 3] = v.w;
  }
  __syncthreads();
  for (int idx = tid; idx < 1024; idx += 256) {
    int e = idx >> 4, t4 = idx & 15;
    float4 v = make_float4(tile[(t4 * 4 + 0) * 65 + e], tile[(t4 * 4 + 1) * 65 + e],
                           tile[(t4 * 4 + 2) * 65 + e], tile[(t4 * 4 + 3) * 65 + e]);
    reinterpret_cast<float4*>(out + ((size_t)(bh * 64 + e)) * 1024 + t0)[t4] = v;
  }
}

// ---- tfq row-norms -> ampsum[bh*2+1][l] ------------------------------------
__device__ __forceinline__ void dev_tfqnorm(int vbid,
                                            const float* __restrict__ tfq,
                                            float* __restrict__ ampsum) {
  const int bh = vbid >> 2, qt = vbid & 3;
  const int b = bh >> 3, h = bh & 7;
  const int l = qt * 256 + threadIdx.x;
  const float4* p4 = reinterpret_cast<const float4*>(
      &tfq[((size_t)(b * L_ + l) * H_ + h) * E_]);
  float s = 0.f;
#pragma unroll
  for (int e4 = 0; e4 < 16; ++e4) {
    float4 v = p4[e4];
    s += v.x * v.x + v.y * v.y + v.z * v.z + v.w * v.w;
  }
  ampsum[(size_t)(bh * 2 + 1) * 1024 + l] = s;
}

// ---- FFT corr amplitude + 64-mode spectra (coalesced, 512 thr) -------------
__device__ __forceinline__ void dev_fft(char* smem, int vbid,
                                        const float* __restrict__ xtq,
                                        const float* __restrict__ xtk,
                                        float* __restrict__ amp2_part,
                                        float* __restrict__ qft,
                                        float* __restrict__ kft) {
  float* zre = reinterpret_cast<float*>(smem);     // [4][1024]
  float* zim = zre + 4096;
  float* ctab = zim + 4096;                        // [512]
  float* stab = ctab + 512;
  const int eg = vbid & 15;
  const int bh = vbid >> 4;
  const int tid = threadIdx.x;
  const float TWO_PI_N = 6.283185307179586f / 1024.0f;

  if (tid < 512) {
    float s, c;
    sincosf(TWO_PI_N * (float)tid, &s, &c);
    ctab[tid] = c; stab[tid] = s;     // W^j = c - i*s
  }
  for (int idx = tid; idx < 1024; idx += 512) {
    int ee = idx >> 8, t4 = idx & 255;
    size_t ro = ((size_t)(bh * 64 + eg * 4 + ee)) * 1024;
    float4 qv = reinterpret_cast<const float4*>(xtq + ro)[t4];
    float4 kv = reinterpret_cast<const float4*>(xtk + ro)[t4];
    *reinterpret_cast<float4*>(&zre[ee * 1024 + t4 * 4]) = qv;
    *reinterpret_cast<float4*>(&zim[ee * 1024 + t4 * 4]) = kv;
  }
  __syncthreads();

  // forward DIF
  for (int s = 0; s < 10; ++s) {
    const int half = 512 >> s;
#pragma unroll
    for (int it = 0; it < 4; ++it) {
      int idx = tid + it * 512;
      int ee = idx >> 9;
      int bf = idx & 511;
      int j = bf & (half - 1);
      int p0 = ((bf >> (9 - s)) << (10 - s)) + j;
      int p1 = p0 + half;
      float ur = zre[ee * 1024 + p0], ui = zim[ee * 1024 + p0];
      float vr = zre[ee * 1024 + p1], vi = zim[ee * 1024 + p1];
      float dr = ur - vr, di = ui - vi;
      zre[ee * 1024 + p0] = ur + vr; zim[ee * 1024 + p0] = ui + vi;
      int twi = j << s;
      float c = ctab[twi], sn = stab[twi];
      zre[ee * 1024 + p1] = fmaf(dr, c, di * sn);
      zim[ee * 1024 + p1] = fmaf(di, c, -dr * sn);
    }
    __syncthreads();
  }

  // Hermitian unpack + P = Fq*conj(Fk); dump modes 0..63
  float pr[8], pi_[8];
#pragma unroll
  for (int it = 0; it < 8; ++it) {
    int idx = tid + it * 512;
    int ee = idx >> 10;
    int p = idx & 1023;
    int m = __brev((unsigned)p) >> 22;
    int mp = (1024 - m) & 1023;
    int pp = __brev((unsigned)mp) >> 22;
    float ar = zre[ee * 1024 + p], ai = zim[ee * 1024 + p];
    float br = zre[ee * 1024 + pp], bi = zim[ee * 1024 + pp];
    float qr = 0.5f * (ar + br), qi = 0.5f * (ai - bi);
    float kr = 0.5f * (ai + bi), ki = -0.5f * (ar - br);
    pr[it]  = fmaf(qr, kr, qi * ki);
    pi_[it] = fmaf(qi, kr, -qr * ki);
    if (m < 64) {
      size_t o = ((size_t)(bh * 64 + eg * 4 + ee) * 64 + m) * 2;
      qft[o] = qr; qft[o + 1] = qi;
      kft[o] = kr; kft[o + 1] = ki;
    }
  }
  __syncthreads();
#pragma unroll
  for (int it = 0; it < 8; ++it) {
    int idx = tid + it * 512;
    int ee = idx >> 10;
    int p = idx & 1023;
    zre[ee * 1024 + p] = pr[it]; zim[ee * 1024 + p] = pi_[it];
  }
  __syncthreads();

  // pair-mix
  for (int idx = tid; idx < 2048; idx += 512) {
    int u = idx >> 10;
    int p = idx & 1023;
    int e0 = 2 * u, e1 = 2 * u + 1;
    float s_r = zre[e0 * 1024 + p] - zim[e1 * 1024 + p];
    float s_i = zim[e0 * 1024 + p] + zre[e1 * 1024 + p];
    zre[e0 * 1024 + p] = s_r; zim[e0 * 1024 + p] = s_i;
  }
  __syncthreads();

  // inverse DIT on slots 0,2
  for (int s = 9; s >= 0; --s) {
    const int half = 512 >> s;
#pragma unroll
    for (int it = 0; it < 2; ++it) {
      int idx = tid + it * 512;
      int ee = (idx >> 9) * 2;
      int bf = idx & 511;
      int j = bf & (half - 1);
      int p0 = ((bf >> (9 - s)) << (10 - s)) + j;
      int p1 = p0 + half;
      int twi = j << s;
      float c = ctab[twi], sn = stab[twi];
      float ur = zre[ee * 1024 + p0], ui = zim[ee * 1024 + p0];
      float wr = zre[ee * 1024 + p1], wi = zim[ee * 1024 + p1];
      float vr = fmaf(wr, c, -wi * sn);
      float vi = fmaf(wi, c, wr * sn);
      zre[ee * 1024 + p0] = ur + vr; zim[ee * 1024 + p0] = ui + vi;
      zre[ee * 1024 + p1] = ur - vr; zim[ee * 1024 + p1] = ui - vi;
    }
    __syncthreads();
  }

  for (int t = tid; t < 1024; t += 512) {
    float r0 = zre[t], i0 = zim[t];
    float r2 = zre[2 * 1024 + t], i2 = zim[2 * 1024 + t];
    amp2_part[(size_t)(bh * 16 + eg) * 1024 + t] =
        fmaf(r0, r0, fmaf(i0, i0, fmaf(r2, r2, i2 * i2)));
  }
}

// ---- reduction + wave top-35 selection for problem p = bh*2+src ------------
__device__ __forceinline__ void dev_sel(char* smem, int vbid,
                                        const float* __restrict__ amp2_part,
                                        const float* __restrict__ ampsum,
                                        int* __restrict__ sel_ws) {
  float* amp = reinterpret_cast<float*>(smem);    // [1024]
  const int p = vbid;
  const int tid = threadIdx.x;

  if ((p & 1) == 0) {
    const int bh = p >> 1;
    for (int t = tid; t < 1024; t += 256) {
      float s = 0.f;
#pragma unroll
      for (int c = 0; c < 16; ++c)
        s += amp2_part[(size_t)(bh * 16 + c) * 1024 + t];
      amp[t] = s;
    }
  } else {
    for (int t = tid; t < 1024; t += 256)
      amp[t] = ampsum[(size_t)p * 1024 + t];
  }
  __syncthreads();

  if (tid < 64) {
    const int lane = tid;
    float val[16];
#pragma unroll
    for (int j = 0; j < 16; ++j) val[j] = amp[j * 64 + lane];

    float bv = -1.f; int bi = lane;
#pragma unroll
    for (int j = 0; j < 16; ++j) {
      if (val[j] > bv) { bv = val[j]; bi = j * 64 + lane; }
    }
    for (int it = 0; it < NTOP; ++it) {
      float v = bv; int i = bi;
#pragma unroll
      for (int d = 1; d < 64; d <<= 1) {
        float ov = __shfl_xor(v, d);
        int oi = __shfl_xor(i, d);
        if (ov > v || (ov == v && oi < i)) { v = ov; i = oi; }
      }
      if (lane == 0) sel_ws[p * 64 + it] = i;
      if ((i & 63) == lane) {
        int jr = i >> 6;
#pragma unroll
        for (int j = 0; j < 16; ++j) if (j == jr) val[j] = -1.f;
        bv = -1.f; bi = lane;
#pragma unroll
        for (int j = 0; j < 16; ++j) {
          if (val[j] > bv) { bv = val[j]; bi = j * 64 + lane; }
        }
      }
    }
  }
}

// ---- sparse attention, 2 rows per thread (plain stores) --------------------
__device__ __forceinline__ void dev_attn2(char* smem, int vbid,
                                          const float* __restrict__ q_g,
                                          const float* __restrict__ tfq,
                                          const float* __restrict__ k_g,
                                          const float* __restrict__ v_g,
                                          const float* __restrict__ wfuse,
                                          const int* __restrict__ sel_ws,
                                          float* __restrict__ out) {
  float4* qs4 = reinterpret_cast<float4*>(smem);   // [2][35][16]
  float4* vs4 = qs4 + 2 * NTOP * 16;
  const int ac = vbid & 7;         // chunk of 128 rows
  const int bh = vbid >> 3;
  const int b = bh >> 3, h = bh & 7;
  const int a0 = ac * 128;
  const int tid = threadIdx.x;

  for (int idx = tid; idx < 2 * NTOP * 16; idx += 256) {
    int src = idx / (NTOP * 16);
    int rem = idx - src * (NTOP * 16);
    int i = rem >> 4, e4 = rem & 15;
    int row = sel_ws[(bh * 2 + src) * 64 + i];
    size_t rb = ((size_t)(b * L_ + row) * H_ + h) * E_;
    const float* qbase = src ? tfq : q_g;
    qs4[(src * NTOP + i) * 16 + e4] = reinterpret_cast<const float4*>(qbase + rb)[e4];
    vs4[(src * NTOP + i) * 16 + e4] = reinterpret_cast<const float4*>(v_g + rb)[e4];
  }
  __syncthreads();

  const int qd = tid & 3, r = tid >> 2;
  const int aA = a0 + r, aB = a0 + 64 + r;
  const int eb = qd * 16;

  size_t krbA = ((size_t)(b * L_ + aA) * H_ + h) * E_;
  size_t krbB = ((size_t)(b * L_ + aB) * H_ + h) * E_;
  const float4* kA = reinterpret_cast<const float4*>(k_g + krbA);
  const float4* kB = reinterpret_cast<const float4*>(k_g + krbB);
  float4 kqA[4], kqB[4];
#pragma unroll
  for (int j4 = 0; j4 < 4; ++j4) { kqA[j4] = kA[qd * 4 + j4]; kqB[j4] = kB[qd * 4 + j4]; }

  float ctA[NTOP], ctfA[NTOP], ctB[NTOP], ctfB[NTOP];
#pragma unroll
  for (int i = 0; i < NTOP; ++i) { ctA[i] = 0.f; ctfA[i] = 0.f; ctB[i] = 0.f; ctfB[i] = 0.f; }

#pragma unroll
  for (int j4 = 0; j4 < 4; ++j4) {
    float4 kvA = kqA[j4], kvB = kqB[j4];
#pragma unroll
    for (int i = 0; i < NTOP; ++i) {
      float4 q4 = qs4[(0 * NTOP + i) * 16 + qd * 4 + j4];
      ctA[i] = fmaf(q4.x, kvA.x, ctA[i]); ctA[i] = fmaf(q4.y, kvA.y, ctA[i]);
      ctA[i] = fmaf(q4.z, kvA.z, ctA[i]); ctA[i] = fmaf(q4.w, kvA.w, ctA[i]);
      ctB[i] = fmaf(q4.x, kvB.x, ctB[i]); ctB[i] = fmaf(q4.y, kvB.y, ctB[i]);
      ctB[i] = fmaf(q4.z, kvB.z, ctB[i]); ctB[i] = fmaf(q4.w, kvB.w, ctB[i]);
      float4 p4 = qs4[(1 * NTOP + i) * 16 + qd * 4 + j4];
      ctfA[i] = fmaf(p4.x, kvA.x, ctfA[i]); ctfA[i] = fmaf(p4.y, kvA.y, ctfA[i]);
      ctfA[i] = fmaf(p4.z, kvA.z, ctfA[i]); ctfA[i] = fmaf(p4.w, kvA.w, ctfA[i]);
      ctfB[i] = fmaf(p4.x, kvB.x, ctfB[i]); ctfB[i] = fmaf(p4.y, kvB.y, ctfB[i]);
      ctfB[i] = fmaf(p4.z, kvB.z, ctfB[i]); ctfB[i] = fmaf(p4.w, kvB.w, ctfB[i]);
    }
  }
#pragma unroll
  for (int i = 0; i < NTOP; ++i) {
    ctA[i] += __shfl_xor(ctA[i], 1);  ctA[i] += __shfl_xor(ctA[i], 2);
    ctfA[i] += __shfl_xor(ctfA[i], 1); ctfA[i] += __shfl_xor(ctfA[i], 2);
    ctB[i] += __shfl_xor(ctB[i], 1);  ctB[i] += __shfl_xor(ctB[i], 2);
    ctfB[i] += __shfl_xor(ctfB[i], 1); ctfB[i] += __shfl_xor(ctfB[i], 2);
  }

  // fuse weights + softmaxes, row A
  {
    float wf0 = wfuse[(h * L_ + aA) * 2 + 0];
    float wf1 = wfuse[(h * L_ + aA) * 2 + 1];
    float wm = fmaxf(wf0, wf1);
    float ew0 = expf(wf0 - wm), ew1 = expf(wf1 - wm);
    float nw0 = ew0 / (ew0 + ew1), nw1 = ew1 / (ew0 + ew1);
    float m = -1e30f;
#pragma unroll
    for (int i = 0; i < NTOP; ++i) { ctA[i] *= SCALE_; m = fmaxf(m, ctA[i]); }
    float sum = 0.f;
#pragma unroll
    for (int i = 0; i < NTOP; ++i) { ctA[i] = expf(ctA[i] - m); sum += ctA[i]; }
    float c = 0.5f * nw0 / sum;
#pragma unroll
    for (int i = 0; i < NTOP; ++i) ctA[i] *= c;
    float m2 = -1e30f;
#pragma unroll
    for (int i = 0; i < NTOP; ++i) { ctfA[i] *= SCALE_; m2 = fmaxf(m2, ctfA[i]); }
    float sum2 = 0.f;
#pragma unroll
    for (int i = 0; i < NTOP; ++i) { ctfA[i] = expf(ctfA[i] - m2); sum2 += ctfA[i]; }
    float c2 = 0.5f * nw1 / sum2;
#pragma unroll
    for (int i = 0; i < NTOP; ++i) ctfA[i] *= c2;
  }
  // row B
  {
    float wf0 = wfuse[(h * L_ + aB) * 2 + 0];
    float wf1 = wfuse[(h * L_ + aB) * 2 + 1];
    float wm = fmaxf(wf0, wf1);
    float ew0 = expf(wf0 - wm), ew1 = expf(wf1 - wm);
    float nw0 = ew0 / (ew0 + ew1), nw1 = ew1 / (ew0 + ew1);
    float m = -1e30f;
#pragma unroll
    for (int i = 0; i < NTOP; ++i) { ctB[i] *= SCALE_; m = fmaxf(m, ctB[i]); }
    float sum = 0.f;
#pragma unroll
    for (int i = 0; i < NTOP; ++i) { ctB[i] = expf(ctB[i] - m); sum += ctB[i]; }
    float c = 0.5f * nw0 / sum;
#pragma unroll
    for (int i = 0; i < NTOP; ++i) ctB[i] *= c;
    float m2 = -1e30f;
#pragma unroll
    for (int i = 0; i < NTOP; ++i) { ctfB[i] *= SCALE_; m2 = fmaxf(m2, ctfB[i]); }
    float sum2 = 0.f;
#pragma unroll
    for (int i = 0; i < NTOP; ++i) { ctfB[i] = expf(ctfB[i] - m2); sum2 += ctfB[i]; }
    float c2 = 0.5f * nw1 / sum2;
#pragma unroll
    for (int i = 0; i < NTOP; ++i) ctfB[i] *= c2;
  }

#pragma unroll
  for (int j4 = 0; j4 < 4; ++j4) {
    float axA = 0.f, ayA = 0.f, azA = 0.f, awA = 0.f;
    float axB = 0.f, ayB = 0.f, azB = 0.f, awB = 0.f;
#pragma unroll
    for (int i = 0; i < NTOP; ++i) {
      float4 v4 = vs4[(0 * NTOP + i) * 16 + qd * 4 + j4];
      axA = fmaf(ctA[i], v4.x, axA); ayA = fmaf(ctA[i], v4.y, ayA);
      azA = fmaf(ctA[i], v4.z, azA); awA = fmaf(ctA[i], v4.w, awA);
      axB = fmaf(ctB[i], v4.x, axB); ayB = fmaf(ctB[i], v4.y, ayB);
      azB = fmaf(ctB[i], v4.z, azB); awB = fmaf(ctB[i], v4.w, awB);
    }
#pragma unroll
    for (int i = 0; i < NTOP; ++i) {
      float4 v4 = vs4[(1 * NTOP + i) * 16 + qd * 4 + j4];
      axA = fmaf(ctfA[i], v4.x, axA); ayA = fmaf(ctfA[i], v4.y, ayA);
      azA = fmaf(ctfA[i], v4.z, azA); awA = fmaf(ctfA[i], v4.w, awA);
      axB = fmaf(ctfB[i], v4.x, axB); ayB = fmaf(ctfB[i], v4.y, ayB);
      azB = fmaf(ctfB[i], v4.z, azB); awB = fmaf(ctfB[i], v4.w, awB);
    }
    int d = eb + j4 * 4;
    out[((size_t)(bh * 64 + d + 0)) * 1024 + aA] = axA;
    out[((size_t)(bh * 64 + d + 1)) * 1024 + aA] = ayA;
    out[((size_t)(bh * 64 + d + 2)) * 1024 + aA] = azA;
    out[((size_t)(bh * 64 + d + 3)) * 1024 + aA] = awA;
    out[((size_t)(bh * 64 + d + 0)) * 1024 + aB] = axB;
    out[((size_t)(bh * 64 + d + 1)) * 1024 + aB] = ayB;
    out[((size_t)(bh * 64 + d + 2)) * 1024 + aB] = azB;
    out[((size_t)(bh * 64 + d + 3)) * 1024 + aB] = awB;
  }
}

// ---- spectral: xqk = ctanh(qft^T kft); xqkv = xqk @ kft^T -------------------
__device__ __forceinline__ void dev_spec12(char* smem, int vbid,
                                           const float* __restrict__ qft,
                                           const float* __restrict__ kft,
                                           float* __restrict__ xre_g,
                                           float* __restrict__ xim_g) {
  float* kre = reinterpret_cast<float*>(smem);    // [64][65]
  float* kim = kre + 4160;
  float* qre = kim + 4160;                        // [64][8]
  float* qim = qre + 512;
  float* tre = qim + 512;                         // [8][64]
  float* tim = tre + 512;
  const int xc = vbid & 7;
  const int bh = vbid >> 3;
  const int tid = threadIdx.x;

  for (int idx = tid; idx < 4096; idx += 256) {
    int e = idx >> 6, y = idx & 63;
    size_t o = ((size_t)(bh * 64 + e) * 64 + y) * 2;
    kre[e * 65 + y] = kft[o]; kim[e * 65 + y] = kft[o + 1];
  }
  for (int idx = tid; idx < 512; idx += 256) {
    int e = idx >> 3, xl = idx & 7;
    size_t o = ((size_t)(bh * 64 + e) * 64 + xc * 8 + xl) * 2;
    qre[e * 8 + xl] = qft[o]; qim[e * 8 + xl] = qft[o + 1];
  }
  __syncthreads();

  const int y = tid & 63, xg = tid >> 6;
#pragma unroll
  for (int xi = 0; xi < 2; ++xi) {
    int xl = xg + xi * 4;
    float ar = 0.f, ai = 0.f;
    for (int e = 0; e < 64; ++e) {
      float a = qre[e * 8 + xl], b = qim[e * 8 + xl];
      float c = kre[e * 65 + y], d = kim[e * 65 + y];
      ar = fmaf(a, c, fmaf(-b, d, ar));
      ai = fmaf(a, d, fmaf(b, c, ai));
    }
    float trv, tiv;
    float x2 = 2.f * ar, y2 = 2.f * ai;
    if (fabsf(x2) > 30.f) {
      trv = copysignf(1.f, ar); tiv = 0.f;
    } else {
      float sh = sinhf(x2), ch = coshf(x2);
      float sn = sinf(y2), cs = cosf(y2);
      float dd = ch + cs;
      trv = sh / dd; tiv = sn / dd;
    }
    tre[xl * 64 + y] = trv; tim[xl * 64 + y] = tiv;
  }
  __syncthreads();

  const int e2 = tid & 63, xg2 = tid >> 6;
#pragma unroll
  for (int xi = 0; xi < 2; ++xi) {
    int xl = xg2 + xi * 4;
    float ar = 0.f, ai = 0.f;
    for (int yy = 0; yy < 64; ++yy) {
      float a = tre[xl * 64 + yy], b = tim[xl * 64 + yy];
      float c = kre[e2 * 65 + yy], d = kim[e2 * 65 + yy];
      ar = fmaf(a, c, fmaf(-b, d, ar));
      ai = fmaf(a, d, fmaf(b, c, ai));
    }
    xre_g[(size_t)bh * 4096 + (xc * 8 + xl) * 64 + e2] = ar;
    xim_g[(size_t)bh * 4096 + (xc * 8 + xl) * 64 + e2] = ai;
  }
}

// ---- w1 einsum, no LDS reduction: thread (x, g) owns o = oc*8+g*2+{0,1} ----
__device__ __forceinline__ void dev_w1(char* smem, int vbid,
                                       const float* __restrict__ xre_g,
                                       const float* __restrict__ xim_g,
                                       const float* __restrict__ w1re,
                                       const float* __restrict__ w1im,
                                       float* __restrict__ xw) {
  float* xre = reinterpret_cast<float*>(smem);    // [64][65]
  float* xim = xre + 4160;
  const int oc = vbid & 7;
  const int bh = vbid >> 3;
  const int h = bh & 7;
  const int tid = threadIdx.x;

  for (int idx = tid; idx < 4096; idx += 256) {
    int x = idx >> 6, e = idx & 63;
    xre[e * 65 + x] = xre_g[(size_t)bh * 4096 + idx];
    xim[e * 65 + x] = xim_g[(size_t)bh * 4096 + idx];
  }
  __syncthreads();

  const int x = tid & 63, g = tid >> 6;
  const int o0 = oc * 8 + g * 2;
  float ar0 = 0.f, ai0 = 0.f, ar1 = 0.f, ai1 = 0.f;
  for (int e = 0; e < 64; ++e) {
    float a = xre[e * 65 + x], b = xim[e * 65 + x];
    size_t wb = (((size_t)h * 64 + e) * 64 + o0) * 64 + x;
    float c0 = w1re[wb], d0 = w1im[wb];
    float c1 = w1re[wb + 64], d1 = w1im[wb + 64];
    ar0 = fmaf(a, c0, fmaf(-b, d0, ar0));
    ai0 = fmaf(a, d0, fmaf(b, c0, ai0));
    ar1 = fmaf(a, c1, fmaf(-b, d1, ar1));
    ai1 = fmaf(a, d1, fmaf(b, c1, ai1));
  }
  const float INV = 1.0f / (512.0f * 512.0f);
  size_t oidx0 = ((size_t)(bh * 64 + o0) * 64 + x) * 2;
  xw[oidx0] = ar0 * INV; xw[oidx0 + 1] = ai0 * INV;
  size_t oidx1 = ((size_t)(bh * 64 + o0 + 1) * 64 + x) * 2;
  xw[oidx1] = ar1 * INV; xw[oidx1 + 1] = ai1 * INV;
}

// ---- final irfft add (plain fmaf; runs after attn has stored out) ----------
__device__ __forceinline__ void dev_final(char* smem, int vbid,
                                          const float* __restrict__ xw,
                                          float* __restrict__ out) {
  float* Xre = reinterpret_cast<float*>(smem);    // [8][64], pre-scaled by 2
  float* Xim = Xre + 512;
  const int tc = vbid & 3;
  const int oc = (vbid >> 2) & 7;
  const int bh = vbid >> 5;
  const int o0 = oc * 8;
  const int tid = threadIdx.x;

  for (int idx = tid; idx < 512; idx += 256) {
    int o = idx >> 6, m = idx & 63;
    size_t s = ((size_t)(bh * 64 + o0 + o) * 64 + m) * 2;
    Xre[o * 64 + m] = 2.f * xw[s]; Xim[o * 64 + m] = 2.f * xw[s + 1];
  }
  __syncthreads();

  const int t = tc * 256 + tid;
  const float HALF_INVN = 0.5f / 1024.0f;
  const float TWO_PI = 6.283185307179586f;
  float th = TWO_PI * (float)t * (1.0f / 1024.0f);
  float s1, c1;
  __sincosf(th, &s1, &c1);
  float cm = c1, sm = s1;

  float acc[8];
#pragma unroll
  for (int o = 0; o < 8; ++o) acc[o] = 0.5f * Xre[o * 64];

  for (int m = 1; m < 64; ++m) {
#pragma unroll
    for (int o = 0; o < 8; ++o) {
      acc[o] = fmaf(Xre[o * 64 + m], cm, acc[o]);
      acc[o] = fmaf(-Xim[o * 64 + m], sm, acc[o]);
    }
    float cn = fmaf(cm, c1, -sm * s1);
    float sn = fmaf(sm, c1, cm * s1);
    cm = cn; sm = sn;
  }
#pragma unroll
  for (int o = 0; o < 8; ++o) {
    size_t oi = ((size_t)(bh * 64 + o0 + o)) * 1024 + t;
    out[oi] = fmaf(acc[o], HALF_INVN, out[oi]);
  }
}

// ============================ fat launches =================================

__global__ __launch_bounds__(256) void k_L1(const float* __restrict__ q,
                                            const float* __restrict__ k,
                                            const float* __restrict__ tfq,
                                            float* __restrict__ xtq,
                                            float* __restrict__ xtk,
                                            float* __restrict__ ampsum) {
  __shared__ __align__(16) char smem[16640];
  if (blockIdx.x < 1024) dev_stage(smem, blockIdx.x, q, k, xtq, xtk);
  else dev_tfqnorm(blockIdx.x - 1024, tfq, ampsum);
}

__global__ __launch_bounds__(512) void k_L2(const float* __restrict__ xtq,
                                            const float* __restrict__ xtk,
                                            float* __restrict__ amp2,
                                            float* __restrict__ qft,
                                            float* __restrict__ kft) {
  __shared__ __align__(16) char smem[36864];
  dev_fft(smem, blockIdx.x, xtq, xtk, amp2, qft, kft);
}

__global__ __launch_bounds__(256) void k_L3(const float* __restrict__ amp2,
                                            const float* __restrict__ ampsum,
                                            int* __restrict__ sel,
                                            const float* __restrict__ qft,
                                            const float* __restrict__ kft,
                                            float* __restrict__ xre_g,
                                            float* __restrict__ xim_g) {
  __shared__ __align__(16) char smem[41472];
  if (blockIdx.x < 64) dev_sel(smem, blockIdx.x, amp2, ampsum, sel);
  else dev_spec12(smem, blockIdx.x - 64, qft, kft, xre_g, xim_g);
}

__global__ __launch_bounds__(256) void k_L4(const float* __restrict__ q,
                                            const float* __restrict__ tfq,
                                            const float* __restrict__ k,
                                            const float* __restrict__ v,
                                            const float* __restrict__ wfuse,
                                            const int* __restrict__ sel,
                                            float* __restrict__ out,
                                            const float* __restrict__ xre_g,
                                            const float* __restrict__ xim_g,
                                            const float* __restrict__ w1re,
                                            const float* __restrict__ w1im,
                                            float* __restrict__ xw) {
  __shared__ __align__(16) char smem[35840];
  if (blockIdx.x < 256) dev_attn2(smem, blockIdx.x, q, tfq, k, v, wfuse, sel, out);
  else dev_w1(smem, blockIdx.x - 256, xre_g, xim_g, w1re, w1im, xw);
}

__global__ __launch_bounds__(256) void k_L5(const float* __restrict__ xw,
                                            float* __restrict__ out) {
  __shared__ __align__(16) char smem[4096];
  dev_final(smem, blockIdx.x, xw, out);
}

// ============================ fallback kernels =============================

__global__ __launch_bounds__(256) void k_fft_s(const float* __restrict__ q_g,
                                               const float* __restrict__ k_g,
                                               float* __restrict__ amp2_part,
                                               float* __restrict__ qft,
                                               float* __restrict__ kft) {
  __shared__ float zre[4][1024], zim[4][1024];
  __shared__ float ctab[512], stab[512];
  const int eg = blockIdx.x & 15;
  const int bh = blockIdx.x >> 4;
  const int b = bh >> 3, h = bh & 7;
  const int tid = threadIdx.x;
  const float TWO_PI_N = 6.283185307179586f / 1024.0f;

  for (int j = tid; j < 512; j += 256) {
    float s, c;
    sincosf(TWO_PI_N * (float)j, &s, &c);
    ctab[j] = c; stab[j] = s;
  }
  for (int t = tid; t < 1024; t += 256) {
    size_t g4 = ((size_t)(b * L_ + t) * H_ + h) * 16 + eg;
    float4 qv = reinterpret_cast<const float4*>(q_g)[g4];
    float4 kv = reinterpret_cast<const float4*>(k_g)[g4];
    zre[0][t] = qv.x; zre[1][t] = qv.y; zre[2][t] = qv.z; zre[3][t] = qv.w;
    zim[0][t] = kv.x; zim[1][t] = kv.y; zim[2][t] = kv.z; zim[3][t] = kv.w;
  }
  __syncthreads();

  for (int s = 0; s < 10; ++s) {
    const int half = 512 >> s;
#pragma unroll
    for (int it = 0; it < 8; ++it) {
      int idx = tid + it * 256;
      int ee = idx >> 9;
      int bf = idx & 511;
      int j = bf & (half - 1);
      int p0 = ((bf >> (9 - s)) << (10 - s)) + j;
      int p1 = p0 + half;
      float ur = zre[ee][p0], ui = zim[ee][p0];
      float vr = zre[ee][p1], vi = zim[ee][p1];
      float dr = ur - vr, di = ui - vi;
      zre[ee][p0] = ur + vr; zim[ee][p0] = ui + vi;
      int twi = j << s;
      float c = ctab[twi], sn = stab[twi];
      zre[ee][p1] = fmaf(dr, c, di * sn);
      zim[ee][p1] = fmaf(di, c, -dr * sn);
    }
    __syncthreads();
  }

  float pr[16], pi_[16];
#pragma unroll
  for (int it = 0; it < 16; ++it) {
    int idx = tid + it * 256;
    int ee = idx >> 10;
    int p = idx & 1023;
    int m = __brev((unsigned)p) >> 22;
    int mp = (1024 - m) & 1023;
    int pp = __brev((unsigned)mp) >> 22;
    float ar = zre[ee][p], ai = zim[ee][p];
    float br = zre[ee][pp], bi = zim[ee][pp];
    float qr = 0.5f * (ar + br), qi = 0.5f * (ai - bi);
    float kr = 0.5f * (ai + bi), ki = -0.5f * (ar - br);
    pr[it]  = fmaf(qr, kr, qi * ki);
    pi_[it] = fmaf(qi, kr, -qr * ki);
    if (m < 64) {
      size_t o = ((size_t)(bh * 64 + eg * 4 + ee) * 64 + m) * 2;
      qft[o] = qr; qft[o + 1] = qi;
      kft[o] = kr; kft[o + 1] = ki;
    }
  }
  __syncthreads();
#pragma unroll
  for (int it = 0; it < 16; ++it) {
    int idx = tid + it * 256;
    int ee = idx >> 10;
    int p = idx & 1023;
    zre[ee][p] = pr[it]; zim[ee][p] = pi_[it];
  }
  __syncthreads();

  for (int idx = tid; idx < 2048; idx += 256) {
    int u = idx >> 10;
    int p = idx & 1023;
    int e0 = 2 * u, e1 = 2 * u + 1;
    float s_r = zre[e0][p] - zim[e1][p];
    float s_i = zim[e0][p] + zre[e1][p];
    zre[e0][p] = s_r; zim[e0][p] = s_i;
  }
  __syncthreads();

  for (int s = 9; s >= 0; --s) {
    const int half = 512 >> s;
#pragma unroll
    for (int it = 0; it < 4; ++it) {
      int idx = tid + it * 256;
      int ee = (idx >> 9) * 2;
      int bf = idx & 511;
      int j = bf & (half - 1);
      int p0 = ((bf >> (9 - s)) << (10 - s)) + j;
      int p1 = p0 + half;
      int twi = j << s;
      float c = ctab[twi], sn = stab[twi];
      float ur = zre[ee][p0], ui = zim[ee][p0];
      float wr = zre[ee][p1], wi = zim[ee][p1];
      float vr = fmaf(wr, c, -wi * sn);
      float vi = fmaf(wi, c, wr * sn);
      zre[ee][p0] = ur + vr; zim[ee][p0] = ui + vi;
      zre[ee][p1] = ur - vr; zim[ee][p1] = ui - vi;
    }
    __syncthreads();
  }

  for (int t = tid; t < 1024; t += 256) {
    float r0 = zre[0][t], i0 = zim[0][t];
    float r2 = zre[2][t], i2 = zim[2][t];
    amp2_part[(size_t)(bh * 16 + eg) * 1024 + t] =
        fmaf(r0, r0, fmaf(i0, i0, fmaf(r2, r2, i2 * i2)));
  }
}

__global__ __launch_bounds__(256) void k_topk(const float* __restrict__ amp2_part,
                                              const float* __restrict__ tfq,
                                              int* __restrict__ sel_ws) {
  __shared__ float amp[1024];
  __shared__ float wv_s[4];
  __shared__ int wi_s[4];
  __shared__ int winner_s;
  const int src = blockIdx.x & 1;
  const int bh = blockIdx.x >> 1;
  const int b = bh >> 3, h = bh & 7;
  const int tid = threadIdx.x;

  if (src == 0) {
    for (int t = tid; t < 1024; t += 256) {
      float s = 0.f;
#pragma unroll
      for (int c = 0; c < 16; ++c) s += amp2_part[(size_t)(bh * 16 + c) * 1024 + t];
      amp[t] = s;
    }
  } else {
    for (int l = tid; l < 1024; l += 256) {
      const float4* p4 = reinterpret_cast<const float4*>(
          &tfq[((size_t)(b * L_ + l) * H_ + h) * E_]);
      float s = 0.f;
#pragma unroll
      for (int e4 = 0; e4 < 16; ++e4) {
        float4 v = p4[e4];
        s += v.x * v.x + v.y * v.y + v.z * v.z + v.w * v.w;
      }
      amp[l] = s;
    }
  }
  __syncthreads();

  float bv = -1.f; int bi = tid;
#pragma unroll
  for (int kk = 0; kk < 4; ++kk) {
    int t = tid + kk * 256;
    float v = amp[t];
    if (v > bv) { bv = v; bi = t; }
  }
  const int lane = tid & 63, w = tid >> 6;

  for (int it = 0; it < NTOP; ++it) {
    float v = bv; int i = bi;
#pragma unroll
    for (int d = 1; d < 64; d <<= 1) {
      float ov = __shfl_xor(v, d);
      int oi = __shfl_xor(i, d);
      if (ov > v || (ov == v && oi < i)) { v = ov; i = oi; }
    }
    if (lane == 0) { wv_s[w] = v; wi_s[w] = i; }
    __syncthreads();
    if (tid == 0) {
      float fv = wv_s[0]; int fi = wi_s[0];
#pragma unroll
      for (int j = 1; j < 4; ++j) {
        if (wv_s[j] > fv || (wv_s[j] == fv && wi_s[j] < fi)) { fv = wv_s[j]; fi = wi_s[j]; }
      }
      winner_s = fi;
      sel_ws[(bh * 2 + src) * 64 + it] = fi;
    }
    __syncthreads();
    int fi = winner_s;
    if ((fi & 255) == tid) {
      amp[fi] = -1.f;
      bv = -1.f; bi = tid;
#pragma unroll
      for (int kk = 0; kk < 4; ++kk) {
        int t = tid + kk * 256;
        float vv = amp[t];
        if (vv > bv) { bv = vv; bi = t; }
      }
    }
  }
}

__global__ __launch_bounds__(256) void k_attn_w(const float* __restrict__ q,
                                                const float* __restrict__ tfq,
                                                const float* __restrict__ k,
                                                const float* __restrict__ v,
                                                const float* __restrict__ wfuse,
                                                const int* __restrict__ sel,
                                                float* __restrict__ out) {
  __shared__ __align__(16) char smem[35840];
  dev_attn2(smem, blockIdx.x, q, tfq, k, v, wfuse, sel, out);
}

__global__ __launch_bounds__(256) void k_spec12_w(const float* __restrict__ qft,
                                                  const float* __restrict__ kft,
                                                  float* __restrict__ xre_g,
                                                  float* __restrict__ xim_g) {
  __shared__ __align__(16) char smem[41472];
  dev_spec12(smem, blockIdx.x, qft, kft, xre_g, xim_g);
}

__global__ __launch_bounds__(256) void k_w1_w(const float* __restrict__ xre_g,
                                              const float* __restrict__ xim_g,
                                              const float* __restrict__ w1re,
                                              const float* __restrict__ w1im,
                                              float* __restrict__ xw) {
  __shared__ __align__(16) char smem[33280];
  dev_w1(smem, blockIdx.x, xre_g, xim_g, w1re, w1im, xw);
}

// ---------------------------------------------------------------------------
extern "C" void kernel_launch(void* const* d_in, const int* in_sizes, int n_in,
                              void* d_out, int out_size, void* d_ws, size_t ws_size,
                              hipStream_t stream) {
  const float* tfq   = (const float*)d_in[0];
  const float* q     = (const float*)d_in[1];
  const float* k     = (const float*)d_in[2];
  const float* v     = (const float*)d_in[3];
  const float* wfuse = (const float*)d_in[5];
  const float* w1re  = (const float*)d_in[6];
  const float* w1im  = (const float*)d_in[7];
  float* out = (float*)d_out;
  float* ws  = (float*)d_ws;

  const size_t STAGED_FLOATS = 5312512;   // ~21.25 MB
  if (ws_size >= STAGED_FLOATS * sizeof(float)) {
    // staged layout:
    //   xtq [0..2097152) | xtk [..4194304) | amp2 [..4718592)
    //   qft [..4980736) | kft [..5242880) | sel [..5246976) | ampsum [..5312512)
    //   xre_g/xim_g/xw alias xtq region (dead after k_L2).
    float* xtq    = ws;
    float* xtk    = ws + 2097152;
    float* amp2   = ws + 4194304;
    float* qft    = ws + 4718592;
    float* kft    = ws + 4980736;
    int*   sel    = (int*)(ws + 5242880);
    float* ampsum = ws + 5246976;
    float* xre_g  = ws;
    float* xim_g  = ws + 131072;
    float* xw     = ws + 262144;

    k_L1<<<1152, 256, 0, stream>>>(q, k, tfq, xtq, xtk, ampsum);
    k_L2<<<512, 512, 0, stream>>>(xtq, xtk, amp2, qft, kft);
    k_L3<<<320, 256, 0, stream>>>(amp2, ampsum, sel, qft, kft, xre_g, xim_g);
    k_L4<<<512, 256, 0, stream>>>(q, tfq, k, v, wfuse, sel, out,
                                  xre_g, xim_g, w1re, w1im, xw);
    k_L5<<<1024, 256, 0, stream>>>(xw, out);
  } else {
    // fallback (4.2 MB layout)
    float* amp2  = ws;
    float* xre_g = ws;
    float* xim_g = ws + 131072;
    float* xw    = ws + 262144;
    float* qft   = ws + 524288;
    float* kft   = ws + 786432;
    int*   sel   = (int*)(ws + 1048576);

    k_fft_s<<<512, 256, 0, stream>>>(q, k, amp2, qft, kft);
    k_topk<<<64, 256, 0, stream>>>(amp2, tfq, sel);
    k_attn_w<<<256, 256, 0, stream>>>(q, tfq, k, v, wfuse, sel, out);
    k_spec12_w<<<256, 256, 0, stream>>>(qft, kft, xre_g, xim_g);
    k_w1_w<<<256, 256, 0, stream>>>(xre_g, xim_g, w1re, w1im, xw);
    k_L5<<<1024, 256, 0, stream>>>(xw, out);
  }
}

// Round 16
// 113.984 us; speedup vs baseline: 1.1300x; 1.1300x over previous
//
#include <hip/hip_runtime.h>
#include <math.h>

#define B_ 4
#define H_ 8
#define L_ 1024
#define E_ 64
#define NTOP 35
#define SCALE_ 0.04419417382415922f  /* 1/sqrt(512) */

// ============================ device roles =================================

// ---- transpose staging x[b][t][h][e] -> xt[bh][e][t] (q and k) -------------
__device__ __forceinline__ void dev_stage(char* smem, int vbid,
                                          const float* __restrict__ q_g,
                                          const float* __restrict__ k_g,
                                          float* __restrict__ xtq,
                                          float* __restrict__ xtk) {
  float* tile = reinterpret_cast<float*>(smem);   // [64][65]
  const int tc = vbid & 15;
  const int src = (vbid >> 4) & 1;
  const int bh = vbid >> 5;
  const int b = bh >> 3, h = bh & 7;
  const int t0 = tc * 64;
  const int tid = threadIdx.x;
  const float* in = src ? k_g : q_g;
  float* out = src ? xtk : xtq;

  for (int idx = tid; idx < 1024; idx += 256) {
    int t = idx >> 4, e4 = idx & 15;
    float4 v = reinterpret_cast<const float4*>(
        in + ((size_t)(b * L_ + t0 + t) * H_ + h) * E_)[e4];
    tile[t * 65 + e4 * 4 + 0] = v.x; tile[t * 65 + e4 * 4 + 1] = v.y;
    tile[t * 65 + e4 * 4 + 2] = v.z; tile[t * 65 + e4 * 4 + 3] = v.w;
  }
  __syncthreads();
  for (int idx = tid; idx < 1024; idx += 256) {
    int e = idx >> 4, t4 = idx & 15;
    float4 v = make_float4(tile[(t4 * 4 + 0) * 65 + e], tile[(t4 * 4 + 1) * 65 + e],
                           tile[(t4 * 4 + 2) * 65 + e], tile[(t4 * 4 + 3) * 65 + e]);
    reinterpret_cast<float4*>(out + ((size_t)(bh * 64 + e)) * 1024 + t0)[t4] = v;
  }
}

// ---- tfq row-norms -> ampsum[bh*2+1][l] ------------------------------------
__device__ __forceinline__ void dev_tfqnorm(int vbid,
                                            const float* __restrict__ tfq,
                                            float* __restrict__ ampsum) {
  const int bh = vbid >> 2, qt = vbid & 3;
  const int b = bh >> 3, h = bh & 7;
  const int l = qt * 256 + threadIdx.x;
  const float4* p4 = reinterpret_cast<const float4*>(
      &tfq[((size_t)(b * L_ + l) * H_ + h) * E_]);
  float s = 0.f;
#pragma unroll
  for (int e4 = 0; e4 < 16; ++e4) {
    float4 v = p4[e4];
    s += v.x * v.x + v.y * v.y + v.z * v.z + v.w * v.w;
  }
  ampsum[(size_t)(bh * 2 + 1) * 1024 + l] = s;
}

// ---- FFT corr amplitude + 64-mode spectra (coalesced, 512 thr) -------------
__device__ __forceinline__ void dev_fft(char* smem, int vbid,
                                        const float* __restrict__ xtq,
                                        const float* __restrict__ xtk,
                                        float* __restrict__ amp2_part,
                                        float* __restrict__ qft,
                                        float* __restrict__ kft) {
  float* zre = reinterpret_cast<float*>(smem);     // [4][1024]
  float* zim = zre + 4096;
  float* ctab = zim + 4096;                        // [512]
  float* stab = ctab + 512;
  const int eg = vbid & 15;
  const int bh = vbid >> 4;
  const int tid = threadIdx.x;
  const float TWO_PI_N = 6.283185307179586f / 1024.0f;

  if (tid < 512) {
    float s, c;
    sincosf(TWO_PI_N * (float)tid, &s, &c);
    ctab[tid] = c; stab[tid] = s;     // W^j = c - i*s
  }
  for (int idx = tid; idx < 1024; idx += 512) {
    int ee = idx >> 8, t4 = idx & 255;
    size_t ro = ((size_t)(bh * 64 + eg * 4 + ee)) * 1024;
    float4 qv = reinterpret_cast<const float4*>(xtq + ro)[t4];
    float4 kv = reinterpret_cast<const float4*>(xtk + ro)[t4];
    *reinterpret_cast<float4*>(&zre[ee * 1024 + t4 * 4]) = qv;
    *reinterpret_cast<float4*>(&zim[ee * 1024 + t4 * 4]) = kv;
  }
  __syncthreads();

  // forward DIF
  for (int s = 0; s < 10; ++s) {
    const int half = 512 >> s;
#pragma unroll
    for (int it = 0; it < 4; ++it) {
      int idx = tid + it * 512;
      int ee = idx >> 9;
      int bf = idx & 511;
      int j = bf & (half - 1);
      int p0 = ((bf >> (9 - s)) << (10 - s)) + j;
      int p1 = p0 + half;
      float ur = zre[ee * 1024 + p0], ui = zim[ee * 1024 + p0];
      float vr = zre[ee * 1024 + p1], vi = zim[ee * 1024 + p1];
      float dr = ur - vr, di = ui - vi;
      zre[ee * 1024 + p0] = ur + vr; zim[ee * 1024 + p0] = ui + vi;
      int twi = j << s;
      float c = ctab[twi], sn = stab[twi];
      zre[ee * 1024 + p1] = fmaf(dr, c, di * sn);
      zim[ee * 1024 + p1] = fmaf(di, c, -dr * sn);
    }
    __syncthreads();
  }

  // Hermitian unpack + P = Fq*conj(Fk); dump modes 0..63
  float pr[8], pi_[8];
#pragma unroll
  for (int it = 0; it < 8; ++it) {
    int idx = tid + it * 512;
    int ee = idx >> 10;
    int p = idx & 1023;
    int m = __brev((unsigned)p) >> 22;
    int mp = (1024 - m) & 1023;
    int pp = __brev((unsigned)mp) >> 22;
    float ar = zre[ee * 1024 + p], ai = zim[ee * 1024 + p];
    float br = zre[ee * 1024 + pp], bi = zim[ee * 1024 + pp];
    float qr = 0.5f * (ar + br), qi = 0.5f * (ai - bi);
    float kr = 0.5f * (ai + bi), ki = -0.5f * (ar - br);
    pr[it]  = fmaf(qr, kr, qi * ki);
    pi_[it] = fmaf(qi, kr, -qr * ki);
    if (m < 64) {
      size_t o = ((size_t)(bh * 64 + eg * 4 + ee) * 64 + m) * 2;
      qft[o] = qr; qft[o + 1] = qi;
      kft[o] = kr; kft[o + 1] = ki;
    }
  }
  __syncthreads();
#pragma unroll
  for (int it = 0; it < 8; ++it) {
    int idx = tid + it * 512;
    int ee = idx >> 10;
    int p = idx & 1023;
    zre[ee * 1024 + p] = pr[it]; zim[ee * 1024 + p] = pi_[it];
  }
  __syncthreads();

  // pair-mix
  for (int idx = tid; idx < 2048; idx += 512) {
    int u = idx >> 10;
    int p = idx & 1023;
    int e0 = 2 * u, e1 = 2 * u + 1;
    float s_r = zre[e0 * 1024 + p] - zim[e1 * 1024 + p];
    float s_i = zim[e0 * 1024 + p] + zre[e1 * 1024 + p];
    zre[e0 * 1024 + p] = s_r; zim[e0 * 1024 + p] = s_i;
  }
  __syncthreads();

  // inverse DIT on slots 0,2
  for (int s = 9; s >= 0; --s) {
    const int half = 512 >> s;
#pragma unroll
    for (int it = 0; it < 2; ++it) {
      int idx = tid + it * 512;
      int ee = (idx >> 9) * 2;
      int bf = idx & 511;
      int j = bf & (half - 1);
      int p0 = ((bf >> (9 - s)) << (10 - s)) + j;
      int p1 = p0 + half;
      int twi = j << s;
      float c = ctab[twi], sn = stab[twi];
      float ur = zre[ee * 1024 + p0], ui = zim[ee * 1024 + p0];
      float wr = zre[ee * 1024 + p1], wi = zim[ee * 1024 + p1];
      float vr = fmaf(wr, c, -wi * sn);
      float vi = fmaf(wi, c, wr * sn);
      zre[ee * 1024 + p0] = ur + vr; zim[ee * 1024 + p0] = ui + vi;
      zre[ee * 1024 + p1] = ur - vr; zim[ee * 1024 + p1] = ui - vi;
    }
    __syncthreads();
  }

  for (int t = tid; t < 1024; t += 512) {
    float r0 = zre[t], i0 = zim[t];
    float r2 = zre[2 * 1024 + t], i2 = zim[2 * 1024 + t];
    amp2_part[(size_t)(bh * 16 + eg) * 1024 + t] =
        fmaf(r0, r0, fmaf(i0, i0, fmaf(r2, r2, i2 * i2)));
  }
}

// ---- reduction + wave top-35 selection for problem p = bh*2+src ------------
__device__ __forceinline__ void dev_sel(char* smem, int vbid,
                                        const float* __restrict__ amp2_part,
                                        const float* __restrict__ ampsum,
                                        int* __restrict__ sel_ws) {
  float* amp = reinterpret_cast<float*>(smem);    // [1024]
  const int p = vbid;
  const int tid = threadIdx.x;

  if ((p & 1) == 0) {
    const int bh = p >> 1;
    for (int t = tid; t < 1024; t += 256) {
      float s = 0.f;
#pragma unroll
      for (int c = 0; c < 16; ++c)
        s += amp2_part[(size_t)(bh * 16 + c) * 1024 + t];
      amp[t] = s;
    }
  } else {
    for (int t = tid; t < 1024; t += 256)
      amp[t] = ampsum[(size_t)p * 1024 + t];
  }
  __syncthreads();

  if (tid < 64) {
    const int lane = tid;
    float val[16];
#pragma unroll
    for (int j = 0; j < 16; ++j) val[j] = amp[j * 64 + lane];

    float bv = -1.f; int bi = lane;
#pragma unroll
    for (int j = 0; j < 16; ++j) {
      if (val[j] > bv) { bv = val[j]; bi = j * 64 + lane; }
    }
    for (int it = 0; it < NTOP; ++it) {
      float v = bv; int i = bi;
#pragma unroll
      for (int d = 1; d < 64; d <<= 1) {
        float ov = __shfl_xor(v, d);
        int oi = __shfl_xor(i, d);
        if (ov > v || (ov == v && oi < i)) { v = ov; i = oi; }
      }
      if (lane == 0) sel_ws[p * 64 + it] = i;
      if ((i & 63) == lane) {
        int jr = i >> 6;
#pragma unroll
        for (int j = 0; j < 16; ++j) if (j == jr) val[j] = -1.f;
        bv = -1.f; bi = lane;
#pragma unroll
        for (int j = 0; j < 16; ++j) {
          if (val[j] > bv) { bv = val[j]; bi = j * 64 + lane; }
        }
      }
    }
  }
}

// ---- sparse attention, 1 row per thread (R12 form; plain stores) -----------
__device__ __forceinline__ void dev_attn(char* smem, int vbid,
                                         const float* __restrict__ q_g,
                                         const float* __restrict__ tfq,
                                         const float* __restrict__ k_g,
                                         const float* __restrict__ v_g,
                                         const float* __restrict__ wfuse,
                                         const int* __restrict__ sel_ws,
                                         float* __restrict__ out) {
  float4* qs4 = reinterpret_cast<float4*>(smem);   // [2][35][16]
  float4* vs4 = qs4 + 2 * NTOP * 16;
  const int ac = vbid & 15;
  const int bh = vbid >> 4;
  const int b = bh >> 3, h = bh & 7;
  const int a0 = ac * 64;
  const int tid = threadIdx.x;

  for (int idx = tid; idx < 2 * NTOP * 16; idx += 256) {
    int src = idx / (NTOP * 16);
    int rem = idx - src * (NTOP * 16);
    int i = rem >> 4, e4 = rem & 15;
    int row = sel_ws[(bh * 2 + src) * 64 + i];
    size_t rb = ((size_t)(b * L_ + row) * H_ + h) * E_;
    const float* qbase = src ? tfq : q_g;
    qs4[(src * NTOP + i) * 16 + e4] = reinterpret_cast<const float4*>(qbase + rb)[e4];
    vs4[(src * NTOP + i) * 16 + e4] = reinterpret_cast<const float4*>(v_g + rb)[e4];
  }
  __syncthreads();

  const int qd = tid & 3, r = tid >> 2;
  const int a = a0 + r;
  const int eb = qd * 16;

  size_t krb = ((size_t)(b * L_ + a) * H_ + h) * E_;
  const float4* k4p = reinterpret_cast<const float4*>(k_g + krb);
  float4 kq[4];
#pragma unroll
  for (int j4 = 0; j4 < 4; ++j4) kq[j4] = k4p[qd * 4 + j4];

  float ct[NTOP], ctf[NTOP];
#pragma unroll
  for (int i = 0; i < NTOP; ++i) { ct[i] = 0.f; ctf[i] = 0.f; }

#pragma unroll
  for (int j4 = 0; j4 < 4; ++j4) {
    float4 kv = kq[j4];
#pragma unroll
    for (int i = 0; i < NTOP; ++i) {
      float4 q4 = qs4[(0 * NTOP + i) * 16 + qd * 4 + j4];
      ct[i] = fmaf(q4.x, kv.x, ct[i]); ct[i] = fmaf(q4.y, kv.y, ct[i]);
      ct[i] = fmaf(q4.z, kv.z, ct[i]); ct[i] = fmaf(q4.w, kv.w, ct[i]);
      float4 p4 = qs4[(1 * NTOP + i) * 16 + qd * 4 + j4];
      ctf[i] = fmaf(p4.x, kv.x, ctf[i]); ctf[i] = fmaf(p4.y, kv.y, ctf[i]);
      ctf[i] = fmaf(p4.z, kv.z, ctf[i]); ctf[i] = fmaf(p4.w, kv.w, ctf[i]);
    }
  }
#pragma unroll
  for (int i = 0; i < NTOP; ++i) {
    ct[i] += __shfl_xor(ct[i], 1);  ct[i] += __shfl_xor(ct[i], 2);
    ctf[i] += __shfl_xor(ctf[i], 1); ctf[i] += __shfl_xor(ctf[i], 2);
  }

  float wf0 = wfuse[(h * L_ + a) * 2 + 0];
  float wf1 = wfuse[(h * L_ + a) * 2 + 1];
  float wm = fmaxf(wf0, wf1);
  float ew0 = expf(wf0 - wm), ew1 = expf(wf1 - wm);
  float nw0 = ew0 / (ew0 + ew1), nw1 = ew1 / (ew0 + ew1);

  {
    float m = -1e30f;
#pragma unroll
    for (int i = 0; i < NTOP; ++i) { ct[i] *= SCALE_; m = fmaxf(m, ct[i]); }
    float sum = 0.f;
#pragma unroll
    for (int i = 0; i < NTOP; ++i) { ct[i] = expf(ct[i] - m); sum += ct[i]; }
    float c = 0.5f * nw0 / sum;
#pragma unroll
    for (int i = 0; i < NTOP; ++i) ct[i] *= c;
  }
  {
    float m = -1e30f;
#pragma unroll
    for (int i = 0; i < NTOP; ++i) { ctf[i] *= SCALE_; m = fmaxf(m, ctf[i]); }
    float sum = 0.f;
#pragma unroll
    for (int i = 0; i < NTOP; ++i) { ctf[i] = expf(ctf[i] - m); sum += ctf[i]; }
    float c = 0.5f * nw1 / sum;
#pragma unroll
    for (int i = 0; i < NTOP; ++i) ctf[i] *= c;
  }
#pragma unroll
  for (int j4 = 0; j4 < 4; ++j4) {
    float ax = 0.f, ay = 0.f, az = 0.f, aw = 0.f;
#pragma unroll
    for (int i = 0; i < NTOP; ++i) {
      float4 v4 = vs4[(0 * NTOP + i) * 16 + qd * 4 + j4];
      ax = fmaf(ct[i], v4.x, ax); ay = fmaf(ct[i], v4.y, ay);
      az = fmaf(ct[i], v4.z, az); aw = fmaf(ct[i], v4.w, aw);
    }
#pragma unroll
    for (int i = 0; i < NTOP; ++i) {
      float4 v4 = vs4[(1 * NTOP + i) * 16 + qd * 4 + j4];
      ax = fmaf(ctf[i], v4.x, ax); ay = fmaf(ctf[i], v4.y, ay);
      az = fmaf(ctf[i], v4.z, az); aw = fmaf(ctf[i], v4.w, aw);
    }
    int d = eb + j4 * 4;
    out[((size_t)(bh * 64 + d + 0)) * 1024 + a] = ax;
    out[((size_t)(bh * 64 + d + 1)) * 1024 + a] = ay;
    out[((size_t)(bh * 64 + d + 2)) * 1024 + a] = az;
    out[((size_t)(bh * 64 + d + 3)) * 1024 + a] = aw;
  }
}

// ---- spectral: xqk = ctanh(qft^T kft); xqkv = xqk @ kft^T -------------------
__device__ __forceinline__ void dev_spec12(char* smem, int vbid,
                                           const float* __restrict__ qft,
                                           const float* __restrict__ kft,
                                           float* __restrict__ xre_g,
                                           float* __restrict__ xim_g) {
  float* kre = reinterpret_cast<float*>(smem);    // [64][65]
  float* kim = kre + 4160;
  float* qre = kim + 4160;                        // [64][8]
  float* qim = qre + 512;
  float* tre = qim + 512;                         // [8][64]
  float* tim = tre + 512;
  const int xc = vbid & 7;
  const int bh = vbid >> 3;
  const int tid = threadIdx.x;

  for (int idx = tid; idx < 4096; idx += 256) {
    int e = idx >> 6, y = idx & 63;
    size_t o = ((size_t)(bh * 64 + e) * 64 + y) * 2;
    kre[e * 65 + y] = kft[o]; kim[e * 65 + y] = kft[o + 1];
  }
  for (int idx = tid; idx < 512; idx += 256) {
    int e = idx >> 3, xl = idx & 7;
    size_t o = ((size_t)(bh * 64 + e) * 64 + xc * 8 + xl) * 2;
    qre[e * 8 + xl] = qft[o]; qim[e * 8 + xl] = qft[o + 1];
  }
  __syncthreads();

  const int y = tid & 63, xg = tid >> 6;
#pragma unroll
  for (int xi = 0; xi < 2; ++xi) {
    int xl = xg + xi * 4;
    float ar = 0.f, ai = 0.f;
    for (int e = 0; e < 64; ++e) {
      float a = qre[e * 8 + xl], b = qim[e * 8 + xl];
      float c = kre[e * 65 + y], d = kim[e * 65 + y];
      ar = fmaf(a, c, fmaf(-b, d, ar));
      ai = fmaf(a, d, fmaf(b, c, ai));
    }
    float trv, tiv;
    float x2 = 2.f * ar, y2 = 2.f * ai;
    if (fabsf(x2) > 30.f) {
      trv = copysignf(1.f, ar); tiv = 0.f;
    } else {
      float sh = sinhf(x2), ch = coshf(x2);
      float sn = sinf(y2), cs = cosf(y2);
      float dd = ch + cs;
      trv = sh / dd; tiv = sn / dd;
    }
    tre[xl * 64 + y] = trv; tim[xl * 64 + y] = tiv;
  }
  __syncthreads();

  const int e2 = tid & 63, xg2 = tid >> 6;
#pragma unroll
  for (int xi = 0; xi < 2; ++xi) {
    int xl = xg2 + xi * 4;
    float ar = 0.f, ai = 0.f;
    for (int yy = 0; yy < 64; ++yy) {
      float a = tre[xl * 64 + yy], b = tim[xl * 64 + yy];
      float c = kre[e2 * 65 + yy], d = kim[e2 * 65 + yy];
      ar = fmaf(a, c, fmaf(-b, d, ar));
      ai = fmaf(a, d, fmaf(b, c, ai));
    }
    xre_g[(size_t)bh * 4096 + (xc * 8 + xl) * 64 + e2] = ar;
    xim_g[(size_t)bh * 4096 + (xc * 8 + xl) * 64 + e2] = ai;
  }
}

// ---- w1 einsum, no LDS reduction: thread (x, g) owns o = oc*8+g*2+{0,1} ----
__device__ __forceinline__ void dev_w1(char* smem, int vbid,
                                       const float* __restrict__ xre_g,
                                       const float* __restrict__ xim_g,
                                       const float* __restrict__ w1re,
                                       const float* __restrict__ w1im,
                                       float* __restrict__ xw) {
  float* xre = reinterpret_cast<float*>(smem);    // [64][65]
  float* xim = xre + 4160;
  const int oc = vbid & 7;
  const int bh = vbid >> 3;
  const int h = bh & 7;
  const int tid = threadIdx.x;

  for (int idx = tid; idx < 4096; idx += 256) {
    int x = idx >> 6, e = idx & 63;
    xre[e * 65 + x] = xre_g[(size_t)bh * 4096 + idx];
    xim[e * 65 + x] = xim_g[(size_t)bh * 4096 + idx];
  }
  __syncthreads();

  const int x = tid & 63, g = tid >> 6;
  const int o0 = oc * 8 + g * 2;
  float ar0 = 0.f, ai0 = 0.f, ar1 = 0.f, ai1 = 0.f;
  for (int e = 0; e < 64; ++e) {
    float a = xre[e * 65 + x], b = xim[e * 65 + x];
    size_t wb = (((size_t)h * 64 + e) * 64 + o0) * 64 + x;
    float c0 = w1re[wb], d0 = w1im[wb];
    float c1 = w1re[wb + 64], d1 = w1im[wb + 64];
    ar0 = fmaf(a, c0, fmaf(-b, d0, ar0));
    ai0 = fmaf(a, d0, fmaf(b, c0, ai0));
    ar1 = fmaf(a, c1, fmaf(-b, d1, ar1));
    ai1 = fmaf(a, d1, fmaf(b, c1, ai1));
  }
  const float INV = 1.0f / (512.0f * 512.0f);
  size_t oidx0 = ((size_t)(bh * 64 + o0) * 64 + x) * 2;
  xw[oidx0] = ar0 * INV; xw[oidx0 + 1] = ai0 * INV;
  size_t oidx1 = ((size_t)(bh * 64 + o0 + 1) * 64 + x) * 2;
  xw[oidx1] = ar1 * INV; xw[oidx1 + 1] = ai1 * INV;
}

// ---- final irfft add (plain fmaf; runs after attn has stored out) ----------
__device__ __forceinline__ void dev_final(char* smem, int vbid,
                                          const float* __restrict__ xw,
                                          float* __restrict__ out) {
  float* Xre = reinterpret_cast<float*>(smem);    // [8][64], pre-scaled by 2
  float* Xim = Xre + 512;
  const int tc = vbid & 3;
  const int oc = (vbid >> 2) & 7;
  const int bh = vbid >> 5;
  const int o0 = oc * 8;
  const int tid = threadIdx.x;

  for (int idx = tid; idx < 512; idx += 256) {
    int o = idx >> 6, m = idx & 63;
    size_t s = ((size_t)(bh * 64 + o0 + o) * 64 + m) * 2;
    Xre[o * 64 + m] = 2.f * xw[s]; Xim[o * 64 + m] = 2.f * xw[s + 1];
  }
  __syncthreads();

  const int t = tc * 256 + tid;
  const float HALF_INVN = 0.5f / 1024.0f;
  const float TWO_PI = 6.283185307179586f;
  float th = TWO_PI * (float)t * (1.0f / 1024.0f);
  float s1, c1;
  __sincosf(th, &s1, &c1);
  float cm = c1, sm = s1;

  float acc[8];
#pragma unroll
  for (int o = 0; o < 8; ++o) acc[o] = 0.5f * Xre[o * 64];

  for (int m = 1; m < 64; ++m) {
#pragma unroll
    for (int o = 0; o < 8; ++o) {
      acc[o] = fmaf(Xre[o * 64 + m], cm, acc[o]);
      acc[o] = fmaf(-Xim[o * 64 + m], sm, acc[o]);
    }
    float cn = fmaf(cm, c1, -sm * s1);
    float sn = fmaf(sm, c1, cm * s1);
    cm = cn; sm = sn;
  }
#pragma unroll
  for (int o = 0; o < 8; ++o) {
    size_t oi = ((size_t)(bh * 64 + o0 + o)) * 1024 + t;
    out[oi] = fmaf(acc[o], HALF_INVN, out[oi]);
  }
}

// ============================ fat launches =================================

__global__ __launch_bounds__(256) void k_L1(const float* __restrict__ q,
                                            const float* __restrict__ k,
                                            const float* __restrict__ tfq,
                                            float* __restrict__ xtq,
                                            float* __restrict__ xtk,
                                            float* __restrict__ ampsum) {
  __shared__ __align__(16) char smem[16640];
  if (blockIdx.x < 1024) dev_stage(smem, blockIdx.x, q, k, xtq, xtk);
  else dev_tfqnorm(blockIdx.x - 1024, tfq, ampsum);
}

__global__ __launch_bounds__(512) void k_L2(const float* __restrict__ xtq,
                                            const float* __restrict__ xtk,
                                            float* __restrict__ amp2,
                                            float* __restrict__ qft,
                                            float* __restrict__ kft) {
  __shared__ __align__(16) char smem[36864];
  dev_fft(smem, blockIdx.x, xtq, xtk, amp2, qft, kft);
}

__global__ __launch_bounds__(256) void k_L3(const float* __restrict__ amp2,
                                            const float* __restrict__ ampsum,
                                            int* __restrict__ sel,
                                            const float* __restrict__ qft,
                                            const float* __restrict__ kft,
                                            float* __restrict__ xre_g,
                                            float* __restrict__ xim_g) {
  __shared__ __align__(16) char smem[41472];
  if (blockIdx.x < 64) dev_sel(smem, blockIdx.x, amp2, ampsum, sel);
  else dev_spec12(smem, blockIdx.x - 64, qft, kft, xre_g, xim_g);
}

__global__ __launch_bounds__(256) void k_L4(const float* __restrict__ q,
                                            const float* __restrict__ tfq,
                                            const float* __restrict__ k,
                                            const float* __restrict__ v,
                                            const float* __restrict__ wfuse,
                                            const int* __restrict__ sel,
                                            float* __restrict__ out,
                                            const float* __restrict__ xre_g,
                                            const float* __restrict__ xim_g,
                                            const float* __restrict__ w1re,
                                            const float* __restrict__ w1im,
                                            float* __restrict__ xw) {
  __shared__ __align__(16) char smem[35840];
  if (blockIdx.x < 512) dev_attn(smem, blockIdx.x, q, tfq, k, v, wfuse, sel, out);
  else dev_w1(smem, blockIdx.x - 512, xre_g, xim_g, w1re, w1im, xw);
}

__global__ __launch_bounds__(256) void k_L5(const float* __restrict__ xw,
                                            float* __restrict__ out) {
  __shared__ __align__(16) char smem[4096];
  dev_final(smem, blockIdx.x, xw, out);
}

// ============================ fallback kernels =============================

__global__ __launch_bounds__(256) void k_fft_s(const float* __restrict__ q_g,
                                               const float* __restrict__ k_g,
                                               float* __restrict__ amp2_part,
                                               float* __restrict__ qft,
                                               float* __restrict__ kft) {
  __shared__ float zre[4][1024], zim[4][1024];
  __shared__ float ctab[512], stab[512];
  const int eg = blockIdx.x & 15;
  const int bh = blockIdx.x >> 4;
  const int b = bh >> 3, h = bh & 7;
  const int tid = threadIdx.x;
  const float TWO_PI_N = 6.283185307179586f / 1024.0f;

  for (int j = tid; j < 512; j += 256) {
    float s, c;
    sincosf(TWO_PI_N * (float)j, &s, &c);
    ctab[j] = c; stab[j] = s;
  }
  for (int t = tid; t < 1024; t += 256) {
    size_t g4 = ((size_t)(b * L_ + t) * H_ + h) * 16 + eg;
    float4 qv = reinterpret_cast<const float4*>(q_g)[g4];
    float4 kv = reinterpret_cast<const float4*>(k_g)[g4];
    zre[0][t] = qv.x; zre[1][t] = qv.y; zre[2][t] = qv.z; zre[3][t] = qv.w;
    zim[0][t] = kv.x; zim[1][t] = kv.y; zim[2][t] = kv.z; zim[3][t] = kv.w;
  }
  __syncthreads();

  for (int s = 0; s < 10; ++s) {
    const int half = 512 >> s;
#pragma unroll
    for (int it = 0; it < 8; ++it) {
      int idx = tid + it * 256;
      int ee = idx >> 9;
      int bf = idx & 511;
      int j = bf & (half - 1);
      int p0 = ((bf >> (9 - s)) << (10 - s)) + j;
      int p1 = p0 + half;
      float ur = zre[ee][p0], ui = zim[ee][p0];
      float vr = zre[ee][p1], vi = zim[ee][p1];
      float dr = ur - vr, di = ui - vi;
      zre[ee][p0] = ur + vr; zim[ee][p0] = ui + vi;
      int twi = j << s;
      float c = ctab[twi], sn = stab[twi];
      zre[ee][p1] = fmaf(dr, c, di * sn);
      zim[ee][p1] = fmaf(di, c, -dr * sn);
    }
    __syncthreads();
  }

  float pr[16], pi_[16];
#pragma unroll
  for (int it = 0; it < 16; ++it) {
    int idx = tid + it * 256;
    int ee = idx >> 10;
    int p = idx & 1023;
    int m = __brev((unsigned)p) >> 22;
    int mp = (1024 - m) & 1023;
    int pp = __brev((unsigned)mp) >> 22;
    float ar = zre[ee][p], ai = zim[ee][p];
    float br = zre[ee][pp], bi = zim[ee][pp];
    float qr = 0.5f * (ar + br), qi = 0.5f * (ai - bi);
    float kr = 0.5f * (ai + bi), ki = -0.5f * (ar - br);
    pr[it]  = fmaf(qr, kr, qi * ki);
    pi_[it] = fmaf(qi, kr, -qr * ki);
    if (m < 64) {
      size_t o = ((size_t)(bh * 64 + eg * 4 + ee) * 64 + m) * 2;
      qft[o] = qr; qft[o + 1] = qi;
      kft[o] = kr; kft[o + 1] = ki;
    }
  }
  __syncthreads();
#pragma unroll
  for (int it = 0; it < 16; ++it) {
    int idx = tid + it * 256;
    int ee = idx >> 10;
    int p = idx & 1023;
    zre[ee][p] = pr[it]; zim[ee][p] = pi_[it];
  }
  __syncthreads();

  for (int idx = tid; idx < 2048; idx += 256) {
    int u = idx >> 10;
    int p = idx & 1023;
    int e0 = 2 * u, e1 = 2 * u + 1;
    float s_r = zre[e0][p] - zim[e1][p];
    float s_i = zim[e0][p] + zre[e1][p];
    zre[e0][p] = s_r; zim[e0][p] = s_i;
  }
  __syncthreads();

  for (int s = 9; s >= 0; --s) {
    const int half = 512 >> s;
#pragma unroll
    for (int it = 0; it < 4; ++it) {
      int idx = tid + it * 256;
      int ee = (idx >> 9) * 2;
      int bf = idx & 511;
      int j = bf & (half - 1);
      int p0 = ((bf >> (9 - s)) << (10 - s)) + j;
      int p1 = p0 + half;
      int twi = j << s;
      float c = ctab[twi], sn = stab[twi];
      float ur = zre[ee][p0], ui = zim[ee][p0];
      float wr = zre[ee][p1], wi = zim[ee][p1];
      float vr = fmaf(wr, c, -wi * sn);
      float vi = fmaf(wi, c, wr * sn);
      zre[ee][p0] = ur + vr; zim[ee][p0] = ui + vi;
      zre[ee][p1] = ur - vr; zim[ee][p1] = ui - vi;
    }
    __syncthreads();
  }

  for (int t = tid; t < 1024; t += 256) {
    float r0 = zre[0][t], i0 = zim[0][t];
    float r2 = zre[2][t], i2 = zim[2][t];
    amp2_part[(size_t)(bh * 16 + eg) * 1024 + t] =
        fmaf(r0, r0, fmaf(i0, i0, fmaf(r2, r2, i2 * i2)));
  }
}

__global__ __launch_bounds__(256) void k_topk(const float* __restrict__ amp2_part,
                                              const float* __restrict__ tfq,
                                              int* __restrict__ sel_ws) {
  __shared__ float amp[1024];
  __shared__ float wv_s[4];
  __shared__ int wi_s[4];
  __shared__ int winner_s;
  const int src = blockIdx.x & 1;
  const int bh = blockIdx.x >> 1;
  const int b = bh >> 3, h = bh & 7;
  const int tid = threadIdx.x;

  if (src == 0) {
    for (int t = tid; t < 1024; t += 256) {
      float s = 0.f;
#pragma unroll
      for (int c = 0; c < 16; ++c) s += amp2_part[(size_t)(bh * 16 + c) * 1024 + t];
      amp[t] = s;
    }
  } else {
    for (int l = tid; l < 1024; l += 256) {
      const float4* p4 = reinterpret_cast<const float4*>(
          &tfq[((size_t)(b * L_ + l) * H_ + h) * E_]);
      float s = 0.f;
#pragma unroll
      for (int e4 = 0; e4 < 16; ++e4) {
        float4 v = p4[e4];
        s += v.x * v.x + v.y * v.y + v.z * v.z + v.w * v.w;
      }
      amp[l] = s;
    }
  }
  __syncthreads();

  float bv = -1.f; int bi = tid;
#pragma unroll
  for (int kk = 0; kk < 4; ++kk) {
    int t = tid + kk * 256;
    float v = amp[t];
    if (v > bv) { bv = v; bi = t; }
  }
  const int lane = tid & 63, w = tid >> 6;

  for (int it = 0; it < NTOP; ++it) {
    float v = bv; int i = bi;
#pragma unroll
    for (int d = 1; d < 64; d <<= 1) {
      float ov = __shfl_xor(v, d);
      int oi = __shfl_xor(i, d);
      if (ov > v || (ov == v && oi < i)) { v = ov; i = oi; }
    }
    if (lane == 0) { wv_s[w] = v; wi_s[w] = i; }
    __syncthreads();
    if (tid == 0) {
      float fv = wv_s[0]; int fi = wi_s[0];
#pragma unroll
      for (int j = 1; j < 4; ++j) {
        if (wv_s[j] > fv || (wv_s[j] == fv && wi_s[j] < fi)) { fv = wv_s[j]; fi = wi_s[j]; }
      }
      winner_s = fi;
      sel_ws[(bh * 2 + src) * 64 + it] = fi;
    }
    __syncthreads();
    int fi = winner_s;
    if ((fi & 255) == tid) {
      amp[fi] = -1.f;
      bv = -1.f; bi = tid;
#pragma unroll
      for (int kk = 0; kk < 4; ++kk) {
        int t = tid + kk * 256;
        float vv = amp[t];
        if (vv > bv) { bv = vv; bi = t; }
      }
    }
  }
}

__global__ __launch_bounds__(256) void k_attn_w(const float* __restrict__ q,
                                                const float* __restrict__ tfq,
                                                const float* __restrict__ k,
                                                const float* __restrict__ v,
                                                const float* __restrict__ wfuse,
                                                const int* __restrict__ sel,
                                                float* __restrict__ out) {
  __shared__ __align__(16) char smem[35840];
  dev_attn(smem, blockIdx.x, q, tfq, k, v, wfuse, sel, out);
}

__global__ __launch_bounds__(256) void k_spec12_w(const float* __restrict__ qft,
                                                  const float* __restrict__ kft,
                                                  float* __restrict__ xre_g,
                                                  float* __restrict__ xim_g) {
  __shared__ __align__(16) char smem[41472];
  dev_spec12(smem, blockIdx.x, qft, kft, xre_g, xim_g);
}

__global__ __launch_bounds__(256) void k_w1_w(const float* __restrict__ xre_g,
                                              const float* __restrict__ xim_g,
                                              const float* __restrict__ w1re,
                                              const float* __restrict__ w1im,
                                              float* __restrict__ xw) {
  __shared__ __align__(16) char smem[33280];
  dev_w1(smem, blockIdx.x, xre_g, xim_g, w1re, w1im, xw);
}

// ---------------------------------------------------------------------------
extern "C" void kernel_launch(void* const* d_in, const int* in_sizes, int n_in,
                              void* d_out, int out_size, void* d_ws, size_t ws_size,
                              hipStream_t stream) {
  const float* tfq   = (const float*)d_in[0];
  const float* q     = (const float*)d_in[1];
  const float* k     = (const float*)d_in[2];
  const float* v     = (const float*)d_in[3];
  const float* wfuse = (const float*)d_in[5];
  const float* w1re  = (const float*)d_in[6];
  const float* w1im  = (const float*)d_in[7];
  float* out = (float*)d_out;
  float* ws  = (float*)d_ws;

  const size_t STAGED_FLOATS = 5312512;   // ~21.25 MB
  if (ws_size >= STAGED_FLOATS * sizeof(float)) {
    // staged layout:
    //   xtq [0..2097152) | xtk [..4194304) | amp2 [..4718592)
    //   qft [..4980736) | kft [..5242880) | sel [..5246976) | ampsum [..5312512)
    //   xre_g/xim_g/xw alias xtq region (dead after k_L2).
    float* xtq    = ws;
    float* xtk    = ws + 2097152;
    float* amp2   = ws + 4194304;
    float* qft    = ws + 4718592;
    float* kft    = ws + 4980736;
    int*   sel    = (int*)(ws + 5242880);
    float* ampsum = ws + 5246976;
    float* xre_g  = ws;
    float* xim_g  = ws + 131072;
    float* xw     = ws + 262144;

    k_L1<<<1152, 256, 0, stream>>>(q, k, tfq, xtq, xtk, ampsum);
    k_L2<<<512, 512, 0, stream>>>(xtq, xtk, amp2, qft, kft);
    k_L3<<<320, 256, 0, stream>>>(amp2, ampsum, sel, qft, kft, xre_g, xim_g);
    k_L4<<<768, 256, 0, stream>>>(q, tfq, k, v, wfuse, sel, out,
                                  xre_g, xim_g, w1re, w1im, xw);
    k_L5<<<1024, 256, 0, stream>>>(xw, out);
  } else {
    // fallback (4.2 MB layout)
    float* amp2  = ws;
    float* xre_g = ws;
    float* xim_g = ws + 131072;
    float* xw    = ws + 262144;
    float* qft   = ws + 524288;
    float* kft   = ws + 786432;
    int*   sel   = (int*)(ws + 1048576);

    k_fft_s<<<512, 256, 0, stream>>>(q, k, amp2, qft, kft);
    k_topk<<<64, 256, 0, stream>>>(amp2, tfq, sel);
    k_attn_w<<<512, 256, 0, stream>>>(q, tfq, k, v, wfuse, sel, out);
    k_spec12_w<<<256, 256, 0, stream>>>(qft, kft, xre_g, xim_g);
    k_w1_w<<<256, 256, 0, stream>>>(xre_g, xim_g, w1re, w1im, xw);
    k_L5<<<1024, 256, 0, stream>>>(xw, out);
  }
}